// Round 6
// baseline (299.934 us; speedup 1.0000x reference)
//
#include <hip/hip_runtime.h>
#include <cstdint>

// ---------------------------------------------------------------------------
// DefaultAttention: x[4,2048,1024] fp32; k=xWk^T+bk, q=xWq^T+bq, v=xWv^T+bv;
// sim = k q^T / 32 (causal tril), attn = softmax(sim), out = attn @ v (fp32).
// R17: scores/pv moved to the qkv-verified BK=32 gemm128 (32 KiB LDS ->
// ~5 blocks/CU = 1280 slots, vs 64 KiB/512 slots) and pv is SPLIT-K:
// R16's queue was a no-op because makespan >= longest job (ts=15 = 16 units)
// and 512 jobs on 512 slots degenerates to the static map. Now pv = 1280
// K-chunks (<=512 wide, max 4 units), big-first via atomic queue, fp32
// atomicAdd into out (zeroed by cvt; per-chunk acc*rv is linear in K).
// scores = 544 jobs, all co-resident in one generation at 32 KiB LDS.
// qkv/gemm128 unchanged (R11-verified 72.5us anchor).
// ---------------------------------------------------------------------------

typedef __attribute__((ext_vector_type(8))) _Float16 f16x8;
typedef __attribute__((ext_vector_type(4))) float f32x4;

__device__ __forceinline__ unsigned short f2h(float x) {
  return __builtin_bit_cast(unsigned short, (_Float16)x);
}

// async global->LDS, 16B per lane; LDS dest = wave-uniform base + lane*16
__device__ __forceinline__ void lds_dma16(const void* g, void* l) {
  auto gp = reinterpret_cast<const __attribute__((address_space(1))) void*>(
      reinterpret_cast<uintptr_t>(g));
  auto lp = reinterpret_cast<__attribute__((address_space(3))) void*>(
      reinterpret_cast<uintptr_t>(l));
  __builtin_amdgcn_global_load_lds(gp, lp, 16, 0, 0);
}

// ---------------------------------------------------------------------------
// gemm128 (BK=32 dbuf, 256 thr, 32 KiB LDS): C[128x128] += A[128xK]*B[128xK]^T
// XOR-swizzled LDS, double-buffered single-barrier pipeline (R4-verified).
// ---------------------------------------------------------------------------
__device__ __forceinline__ void gemm128(const unsigned short* __restrict__ Ag,
                                        const unsigned short* __restrict__ Bg,
                                        int lda, int ldb, int nk,
                                        unsigned short* As, unsigned short* Bs,
                                        f32x4 acc[4][4]) {
  const int tid = threadIdx.x;
  const int lane = tid & 63, wave = tid >> 6;
  const int wm = wave >> 1, wn = wave & 1;
  const int sr = lane >> 2;                               // staging row in chunk
  const int scb = (((lane & 3) ^ ((lane >> 3) & 3)) * 8); // swizzled src col
  const int rr = lane & 15, qq = lane >> 4;
  const int slot = ((qq ^ ((rr >> 1) & 3)) * 8);          // swizzled read col

#pragma unroll
  for (int i = 0; i < 4; ++i)
#pragma unroll
    for (int j = 0; j < 4; ++j) {
      f32x4 z = {0.f, 0.f, 0.f, 0.f};
      acc[i][j] = z;
    }

#pragma unroll
  for (int c = 0; c < 2; ++c) {
    int chunk = wave * 2 + c;
    int row = chunk * 16 + sr;
    lds_dma16(Ag + (size_t)row * lda + scb, As + chunk * 512);
    lds_dma16(Bg + (size_t)row * ldb + scb, Bs + chunk * 512);
  }

  int buf = 0;
  for (int k0 = 0; k0 < nk; k0 += 32) {
    __syncthreads();  // drains staging issued one compute-phase ago
    const int kn = k0 + 32;
    if (kn < nk) {
      unsigned short* An = As + (buf ^ 1) * 4096;
      unsigned short* Bn = Bs + (buf ^ 1) * 4096;
#pragma unroll
      for (int c = 0; c < 2; ++c) {
        int chunk = wave * 2 + c;
        int row = chunk * 16 + sr;
        lds_dma16(Ag + (size_t)row * lda + kn + scb, An + chunk * 512);
        lds_dma16(Bg + (size_t)row * ldb + kn + scb, Bn + chunk * 512);
      }
    }

    f16x8 af[4], bf[4];
    const unsigned short* Ar = As + buf * 4096 + (wm * 64 + rr) * 32 + slot;
    const unsigned short* Br = Bs + buf * 4096 + (wn * 64 + rr) * 32 + slot;
#pragma unroll
    for (int i = 0; i < 4; ++i) af[i] = *(const f16x8*)(Ar + i * 512);
#pragma unroll
    for (int j = 0; j < 4; ++j) bf[j] = *(const f16x8*)(Br + j * 512);
#pragma unroll
    for (int i = 0; i < 4; ++i)
#pragma unroll
      for (int j = 0; j < 4; ++j)
        acc[i][j] = __builtin_amdgcn_mfma_f32_16x16x32_f16(af[i], bf[j],
                                                           acc[i][j], 0, 0, 0);
    buf ^= 1;
  }
}

// ---------------------------------------------------------------------------
// fp32 -> f16 convert: x then Wk,Wq,Wv into contiguous [xh | wh];
// tail blocks zero rsum (8192 floats), queue counters, and out (32 MB fp32,
// needed by pv's split-K atomic accumulation).
// ---------------------------------------------------------------------------
__global__ void cvt_kernel(const float* __restrict__ x,
                           const float* __restrict__ w0,
                           const float* __restrict__ w1,
                           const float* __restrict__ w2,
                           unsigned short* __restrict__ dst,
                           float* __restrict__ rsum, int* __restrict__ cnt,
                           float* __restrict__ out) {
  int i = blockIdx.x * 256 + threadIdx.x;
  if (i >= 2885632) {                      // out zero region
    int o = i - 2885632;
    float4 z = {0.f, 0.f, 0.f, 0.f};
    ((float4*)out)[o] = z;
    return;
  }
  if (i >= 2883584) {                      // rsum + counters
    int z2 = i - 2883584;
    float4 z = {0.f, 0.f, 0.f, 0.f};
    ((float4*)rsum)[z2] = z;
    if (z2 == 0) { cnt[0] = 0; cnt[1] = 0; }
    return;
  }
  const float* s;
  size_t si;
  if (i < 2097152) {
    s = x; si = i;
  } else {
    int j = i - 2097152;
    int z = j >> 18;
    s = (z == 0) ? w0 : ((z == 1) ? w1 : w2);
    si = j & 262143;
  }
  float4 f = ((const float4*)s)[si];
  ushort4 u;
  u.x = f2h(f.x); u.y = f2h(f.y); u.z = f2h(f.z); u.w = f2h(f.w);
  ((ushort4*)dst)[i] = u;
}

// ---------------------------------------------------------------------------
// QKV projection, grid (24, 64): x = z*8 + tn (z fast -> xh slab shared by
// all 24 blocks of a tm), y = tm.   [R11-verified, 72.5us]
//   z=0/1: C[t, f] = xh[t-slab] . W[f-tile]^T  -> kh/qh[t*1024 + f]
//   z=2  : C[d, t] = Wv[d-tile] . xh[t-slab]^T -> vT[b][d][t]  (direct)
// ---------------------------------------------------------------------------
__global__ __launch_bounds__(256) void qkv_gemm_kernel(
    const unsigned short* __restrict__ xh, const unsigned short* __restrict__ wh,
    const float* __restrict__ bk, const float* __restrict__ bq,
    const float* __restrict__ bv, unsigned short* __restrict__ kh,
    unsigned short* __restrict__ qh, unsigned short* __restrict__ vT) {
  __shared__ unsigned short As[2 * 128 * 32], Bs[2 * 128 * 32];
  const int tn = blockIdx.x & 7, z = blockIdx.x >> 3;
  const unsigned short* W = wh + (size_t)z * 1048576;
  const int tm = blockIdx.y;

  const unsigned short* Ag = (z == 2) ? (W + (size_t)tn * 128 * 1024)
                                      : (xh + (size_t)tm * 128 * 1024);
  const unsigned short* Bg = (z == 2) ? (xh + (size_t)tm * 128 * 1024)
                                      : (W + (size_t)tn * 128 * 1024);

  f32x4 acc[4][4];
  gemm128(Ag, Bg, 1024, 1024, 1024, As, Bs, acc);

  const int lane = threadIdx.x & 63, wave = threadIdx.x >> 6;
  const int wm = wave >> 1, wn = wave & 1, rr = lane & 15, qq = lane >> 4;

  if (z == 2) {
    // rows = d, cols = t; bias is per-row (float4 over reg)
#pragma unroll
    for (int i = 0; i < 4; ++i) {
      int d0 = tn * 128 + wm * 64 + i * 16 + qq * 4;
      float4 bi = *(const float4*)(bv + d0);
      float bir[4] = {bi.x, bi.y, bi.z, bi.w};
#pragma unroll
      for (int reg = 0; reg < 4; ++reg) {
        int d = d0 + reg;
#pragma unroll
        for (int j = 0; j < 4; ++j) {
          int tg = tm * 128 + wn * 64 + j * 16 + rr;  // global token
          int bb = tg >> 11, tt = tg & 2047;
          vT[((size_t)(bb * 1024 + d)) * 2048 + tt] =
              f2h(acc[i][j][reg] + bir[reg]);
        }
      }
    }
  } else {
    const float* bias = (z == 0) ? bk : bq;
    unsigned short* dst = (z == 0) ? kh : qh;
    float bj[4];
#pragma unroll
    for (int j = 0; j < 4; ++j)
      bj[j] = bias[tn * 128 + wn * 64 + j * 16 + rr];
#pragma unroll
    for (int i = 0; i < 4; ++i)
#pragma unroll
      for (int reg = 0; reg < 4; ++reg) {
        int gm = tm * 128 + wm * 64 + i * 16 + qq * 4 + reg;
#pragma unroll
        for (int j = 0; j < 4; ++j) {
          int gc = tn * 128 + wn * 64 + j * 16 + rr;
          dst[(size_t)gm * 1024 + gc] = f2h(acc[i][j][reg] + bj[j]);
        }
      }
  }
}

// ---------------------------------------------------------------------------
// scores: P[b,s,t] = exp(k[s].q[t]/32 - 4) for t<=s else 0  (f16), plus
// fused row-sum atomics. Triangular grid (136,4). BK=32 gemm128 (32 KiB LDS
// -> ~5 blocks/CU; all 544 blocks co-resident in one generation).
// ---------------------------------------------------------------------------
__global__ __launch_bounds__(256) void scores_kernel(
    const unsigned short* __restrict__ kh, const unsigned short* __restrict__ qh,
    unsigned short* __restrict__ P, float* __restrict__ rsum) {
  const int b = blockIdx.y;
  int idx = blockIdx.x;
  int ts = (int)((sqrtf(8.0f * idx + 1.0f) - 1.0f) * 0.5f);
  while ((ts + 1) * (ts + 2) / 2 <= idx) ++ts;
  while (ts * (ts + 1) / 2 > idx) --ts;
  const int tt = idx - ts * (ts + 1) / 2;
  __shared__ unsigned short As[2 * 128 * 32], Bs[2 * 128 * 32];

  f32x4 acc[4][4];
  gemm128(kh + ((size_t)(b * 2048 + ts * 128)) * 1024,
          qh + ((size_t)(b * 2048 + tt * 128)) * 1024,
          1024, 1024, 1024, As, Bs, acc);

  const int lane = threadIdx.x & 63, wave = threadIdx.x >> 6;
  const int wm = wave >> 1, wn = wave & 1, rr = lane & 15, qq = lane >> 4;
  unsigned short* Pb = P + (size_t)b * 2048 * 2048;
  float* rs = rsum + b * 2048;
#pragma unroll
  for (int i = 0; i < 4; ++i)
#pragma unroll
    for (int reg = 0; reg < 4; ++reg) {
      int srow = ts * 128 + wm * 64 + i * 16 + qq * 4 + reg;
      float p = 0.f;
#pragma unroll
      for (int j = 0; j < 4; ++j) {
        int tcol = tt * 128 + wn * 64 + j * 16 + rr;
        float e = (tcol <= srow) ? __expf(acc[i][j][reg] * 0.03125f - 4.0f)
                                 : 0.0f;
        Pb[(size_t)srow * 2048 + tcol] = f2h(e);
        p += e;
      }
#pragma unroll
      for (int off = 1; off < 16; off <<= 1) p += __shfl_xor(p, off);
      if (rr == 0) atomicAdd(rs + srow, p);
    }
}

// ---------------------------------------------------------------------------
// pv (persistent, SPLIT-K): out[b,s,d] += (1/rsum[b,s]) * P[b,s,kc] * vT
// 1280 K-chunk jobs (<=512 wide), big-K-first via atomic queue (cnt[1]),
// grid 1024, BK=32 gemm128 (32 KiB LDS). fp32 atomicAdd into zeroed out.
// Job table (descending chunk count): ts 15..12: 4 chunks, 11..8: 3,
// 7..4: 2, 3..0: 1;  j -> (ts,b,td,kc) decoded by range.
// ---------------------------------------------------------------------------
__global__ __launch_bounds__(256) void pv_gemm_kernel(
    const unsigned short* __restrict__ P, const unsigned short* __restrict__ vT,
    const float* __restrict__ rsum, float* __restrict__ out,
    int* __restrict__ cnt) {
  __shared__ unsigned short As[2 * 128 * 32], Bs[2 * 128 * 32];
  __shared__ int js;
  const int tid = threadIdx.x;

  for (;;) {
    if (tid == 0) js = atomicAdd(cnt + 1, 1);
    __syncthreads();
    const int j = js;
    if (j >= 1280) return;  // uniform: all threads read the same js

    int ts, b, td, kc;
    if (j < 512) {
      ts = 15 - (j >> 7); int r = j & 127;
      b = r >> 5; td = (r >> 2) & 7; kc = r & 3;
    } else if (j < 896) {
      int q = j - 512; ts = 11 - q / 96; int r = q % 96;
      b = r / 24; int r2 = r % 24; td = r2 / 3; kc = r2 % 3;
    } else if (j < 1152) {
      int q = j - 896; ts = 7 - (q >> 6); int r = q & 63;
      b = r >> 4; td = (r >> 1) & 7; kc = r & 1;
    } else {
      int q = j - 1152; ts = 3 - (q >> 5); int r = q & 31;
      b = r >> 3; td = r & 7; kc = 0;
    }
    const int kbeg = kc * 512;
    const int nk = min(512, (ts + 1) * 128 - kbeg);

    f32x4 acc[4][4];
    gemm128(P + ((size_t)(b * 2048 + ts * 128)) * 2048 + kbeg,
            vT + ((size_t)(b * 1024 + td * 128)) * 2048 + kbeg,
            2048, 2048, nk, As, Bs, acc);
    // gemm's internal barriers order all lanes' js-read before the next
    // iteration's js-write by thread 0.

    const int lane = tid & 63, wave = tid >> 6;
    const int wm = wave >> 1, wn = wave & 1, rr = lane & 15, qq = lane >> 4;
#pragma unroll
    for (int i = 0; i < 4; ++i) {
      int s0 = ts * 128 + wm * 64 + i * 16 + qq * 4;
      float4 r4 = *(const float4*)(rsum + b * 2048 + s0);
      float rv[4] = {__builtin_amdgcn_rcpf(r4.x), __builtin_amdgcn_rcpf(r4.y),
                     __builtin_amdgcn_rcpf(r4.z), __builtin_amdgcn_rcpf(r4.w)};
#pragma unroll
      for (int reg = 0; reg < 4; ++reg) {
        int srow = s0 + reg;
#pragma unroll
        for (int jj = 0; jj < 4; ++jj) {
          int dcol = td * 128 + wn * 64 + jj * 16 + rr;
          atomicAdd(&out[((size_t)(b * 2048 + srow)) * 1024 + dcol],
                    acc[i][jj][reg] * rv[reg]);
        }
      }
    }
  }
}

// ---------------------------------------------------------------------------
// launch
// ---------------------------------------------------------------------------
extern "C" void kernel_launch(void* const* d_in, const int* in_sizes, int n_in,
                              void* d_out, int out_size, void* d_ws,
                              size_t ws_size, hipStream_t stream) {
  const float* x  = (const float*)d_in[0];
  const float* Wk = (const float*)d_in[1];
  const float* bk = (const float*)d_in[2];
  const float* Wq = (const float*)d_in[3];
  const float* bq = (const float*)d_in[4];
  const float* Wv = (const float*)d_in[5];
  const float* bv = (const float*)d_in[6];
  float* out = (float*)d_out;

  char* ws = (char*)d_ws;
  const size_t MB = 1ull << 20;
  // Aliased layout (86 MB + 32 KB): P overlays xh/wh (dead by scores).
  unsigned short* xh = (unsigned short*)(ws + 0);        // 16 MB  [0,16)
  unsigned short* wh = (unsigned short*)(ws + 16 * MB);  //  6 MB  [16,22)
  unsigned short* P  = (unsigned short*)(ws + 0);        // 32 MB  [0,32) alias
  int* cnt = (int*)(ws + 36 * MB);                       // queue counters
  unsigned short* kh = (unsigned short*)(ws + 38 * MB);  // 16 MB  [38,54)
  unsigned short* qh = (unsigned short*)(ws + 54 * MB);  // 16 MB  [54,70)
  unsigned short* vT = (unsigned short*)(ws + 70 * MB);  // 16 MB  [70,86)
  float* rsum = (float*)(ws + 86 * MB);                  // 32 KB

  // 1) converts (x + 3 W) + zero-init of rsum, counters, out
  cvt_kernel<<<19464, 256, 0, stream>>>(x, Wk, Wq, Wv, xh, rsum, cnt, out);
  // 2) QKV projections (R11 gemm128); z=2 operand-swapped -> writes vT
  qkv_gemm_kernel<<<dim3(24, 64), 256, 0, stream>>>(xh, wh, bk, bq, bv,
                                                    kh, qh, vT);
  // 3) masked exp(scores) + fused row-sum atomics (BK=32, one generation)
  scores_kernel<<<dim3(136, 4), 256, 0, stream>>>(kh, qh, P, rsum);
  // 4) (P @ v) * (1/rsum) -> out (persistent split-K queue, big-K-first)
  pv_gemm_kernel<<<1024, 256, 0, stream>>>(P, vT, rsum, out, cnt);
}

// Round 7
// 260.796 us; speedup vs baseline: 1.1501x; 1.1501x over previous
//
#include <hip/hip_runtime.h>
#include <cstdint>

// ---------------------------------------------------------------------------
// DefaultAttention: x[4,2048,1024] fp32; k=xWk^T+bk, q=xWq^T+bq, v=xWv^T+bv;
// sim = k q^T / 32 (causal tril), attn = softmax(sim), out = attn @ v (fp32).
// R18: scores/pv restored to the R11-verified BK=64 gemm128_k64 (R6's BK=32
// switch regressed both: these kernels are DMA-latency/barrier-bound at
// 2 blocks/CU, so halving per-K-tile barrier spacing doubled the stalls).
// pv keeps R6's ONE validated idea -- split-K -- but 2-way only (ts>=8 split
// at K=1024) with a STATIC LPT packing: 768 jobs in exactly 512 bins
// (= resident slots), max bin 9 K-units (vs 16 before), <=2 jobs/block,
// no queue. Split tiles atomicAdd into out (zeroed by cvt, ~34 MB atomics);
// unsplit tiles plain-store. Per-chunk acc*(1/rsum) is K-linear -> exact.
// qkv unchanged (R11-verified 72.5us anchor).
// ---------------------------------------------------------------------------

typedef __attribute__((ext_vector_type(8))) _Float16 f16x8;
typedef __attribute__((ext_vector_type(4))) float f32x4;

__device__ __forceinline__ unsigned short f2h(float x) {
  return __builtin_bit_cast(unsigned short, (_Float16)x);
}

// async global->LDS, 16B per lane; LDS dest = wave-uniform base + lane*16
__device__ __forceinline__ void lds_dma16(const void* g, void* l) {
  auto gp = reinterpret_cast<const __attribute__((address_space(1))) void*>(
      reinterpret_cast<uintptr_t>(g));
  auto lp = reinterpret_cast<__attribute__((address_space(3))) void*>(
      reinterpret_cast<uintptr_t>(l));
  __builtin_amdgcn_global_load_lds(gp, lp, 16, 0, 0);
}

// ---------------------------------------------------------------------------
// gemm128 (BK=32 dbuf, 256 thr, 32 KiB LDS): C[128x128] += A[128xK]*B[128xK]^T
// XOR-swizzled LDS, double-buffered single-barrier pipeline (R4-verified).
// Used by qkv only (occupancy-sensitive multi-round launch).
// ---------------------------------------------------------------------------
__device__ __forceinline__ void gemm128(const unsigned short* __restrict__ Ag,
                                        const unsigned short* __restrict__ Bg,
                                        int lda, int ldb, int nk,
                                        unsigned short* As, unsigned short* Bs,
                                        f32x4 acc[4][4]) {
  const int tid = threadIdx.x;
  const int lane = tid & 63, wave = tid >> 6;
  const int wm = wave >> 1, wn = wave & 1;
  const int sr = lane >> 2;                               // staging row in chunk
  const int scb = (((lane & 3) ^ ((lane >> 3) & 3)) * 8); // swizzled src col
  const int rr = lane & 15, qq = lane >> 4;
  const int slot = ((qq ^ ((rr >> 1) & 3)) * 8);          // swizzled read col

#pragma unroll
  for (int i = 0; i < 4; ++i)
#pragma unroll
    for (int j = 0; j < 4; ++j) {
      f32x4 z = {0.f, 0.f, 0.f, 0.f};
      acc[i][j] = z;
    }

#pragma unroll
  for (int c = 0; c < 2; ++c) {
    int chunk = wave * 2 + c;
    int row = chunk * 16 + sr;
    lds_dma16(Ag + (size_t)row * lda + scb, As + chunk * 512);
    lds_dma16(Bg + (size_t)row * ldb + scb, Bs + chunk * 512);
  }

  int buf = 0;
  for (int k0 = 0; k0 < nk; k0 += 32) {
    __syncthreads();  // drains staging issued one compute-phase ago
    const int kn = k0 + 32;
    if (kn < nk) {
      unsigned short* An = As + (buf ^ 1) * 4096;
      unsigned short* Bn = Bs + (buf ^ 1) * 4096;
#pragma unroll
      for (int c = 0; c < 2; ++c) {
        int chunk = wave * 2 + c;
        int row = chunk * 16 + sr;
        lds_dma16(Ag + (size_t)row * lda + kn + scb, An + chunk * 512);
        lds_dma16(Bg + (size_t)row * ldb + kn + scb, Bn + chunk * 512);
      }
    }

    f16x8 af[4], bf[4];
    const unsigned short* Ar = As + buf * 4096 + (wm * 64 + rr) * 32 + slot;
    const unsigned short* Br = Bs + buf * 4096 + (wn * 64 + rr) * 32 + slot;
#pragma unroll
    for (int i = 0; i < 4; ++i) af[i] = *(const f16x8*)(Ar + i * 512);
#pragma unroll
    for (int j = 0; j < 4; ++j) bf[j] = *(const f16x8*)(Br + j * 512);
#pragma unroll
    for (int i = 0; i < 4; ++i)
#pragma unroll
      for (int j = 0; j < 4; ++j)
        acc[i][j] = __builtin_amdgcn_mfma_f32_16x16x32_f16(af[i], bf[j],
                                                           acc[i][j], 0, 0, 0);
    buf ^= 1;
  }
}

// ---------------------------------------------------------------------------
// gemm128_k64 (BK=64 dbuf, 256 thr, 64 KiB LDS): scores/pv workhorse.
// R3-verified swizzle: LDS slot s of row r holds src col-block s^(r&7);
// readers use slot (cb ^ (rr&7)). 32 MFMA/wave between barriers.
// ---------------------------------------------------------------------------
__device__ __forceinline__ void gemm128_k64(
    const unsigned short* __restrict__ Ag, const unsigned short* __restrict__ Bg,
    int lda, int ldb, int nk, unsigned short* As, unsigned short* Bs,
    f32x4 acc[4][4]) {
  const int tid = threadIdx.x;
  const int lane = tid & 63, wave = tid >> 6;
  const int wm = wave >> 1, wn = wave & 1;
  const int sr = lane >> 3;                     // staging row within 8-row chunk
  const int scb = ((lane & 7) ^ sr) * 8;        // swizzled source col (ush)
  const int rr = lane & 15, qq = lane >> 4;
  const int slot0 = ((qq) ^ (rr & 7)) * 8;      // k-half 0 read col
  const int slot1 = ((4 + qq) ^ (rr & 7)) * 8;  // k-half 1 read col

#pragma unroll
  for (int i = 0; i < 4; ++i)
#pragma unroll
    for (int j = 0; j < 4; ++j) {
      f32x4 z = {0.f, 0.f, 0.f, 0.f};
      acc[i][j] = z;
    }

  // prologue: stage k=0 into buf 0 (16 chunks of 8 rows; wave w: 4w..4w+3)
#pragma unroll
  for (int c = 0; c < 4; ++c) {
    int chunk = wave * 4 + c;
    int row = chunk * 8 + sr;
    lds_dma16(Ag + (size_t)row * lda + scb, As + chunk * 512);
    lds_dma16(Bg + (size_t)row * ldb + scb, Bs + chunk * 512);
  }

  int buf = 0;
  for (int k0 = 0; k0 < nk; k0 += 64) {
    __syncthreads();  // drains staging issued one compute-phase ago
    const int kn = k0 + 64;
    if (kn < nk) {
      unsigned short* An = As + (buf ^ 1) * 8192;
      unsigned short* Bn = Bs + (buf ^ 1) * 8192;
#pragma unroll
      for (int c = 0; c < 4; ++c) {
        int chunk = wave * 4 + c;
        int row = chunk * 8 + sr;
        lds_dma16(Ag + (size_t)row * lda + kn + scb, An + chunk * 512);
        lds_dma16(Bg + (size_t)row * ldb + kn + scb, Bn + chunk * 512);
      }
    }

    const unsigned short* Ar = As + buf * 8192 + (wm * 64 + rr) * 64;
    const unsigned short* Br = Bs + buf * 8192 + (wn * 64 + rr) * 64;
    {
      f16x8 af[4], bf[4];
#pragma unroll
      for (int i = 0; i < 4; ++i) af[i] = *(const f16x8*)(Ar + i * 1024 + slot0);
#pragma unroll
      for (int j = 0; j < 4; ++j) bf[j] = *(const f16x8*)(Br + j * 1024 + slot0);
#pragma unroll
      for (int i = 0; i < 4; ++i)
#pragma unroll
        for (int j = 0; j < 4; ++j)
          acc[i][j] = __builtin_amdgcn_mfma_f32_16x16x32_f16(af[i], bf[j],
                                                             acc[i][j], 0, 0, 0);
    }
    {
      f16x8 af[4], bf[4];
#pragma unroll
      for (int i = 0; i < 4; ++i) af[i] = *(const f16x8*)(Ar + i * 1024 + slot1);
#pragma unroll
      for (int j = 0; j < 4; ++j) bf[j] = *(const f16x8*)(Br + j * 1024 + slot1);
#pragma unroll
      for (int i = 0; i < 4; ++i)
#pragma unroll
        for (int j = 0; j < 4; ++j)
          acc[i][j] = __builtin_amdgcn_mfma_f32_16x16x32_f16(af[i], bf[j],
                                                             acc[i][j], 0, 0, 0);
    }
    buf ^= 1;
  }
}

// ---------------------------------------------------------------------------
// fp32 -> f16 convert: x then Wk,Wq,Wv into contiguous [xh | wh];
// tail blocks zero rsum (8192 floats) and out (32 MB fp32, needed by pv's
// split-K atomic accumulation). Grid 19464*256 = 4982784 threads exactly.
// ---------------------------------------------------------------------------
__global__ void cvt_kernel(const float* __restrict__ x,
                           const float* __restrict__ w0,
                           const float* __restrict__ w1,
                           const float* __restrict__ w2,
                           unsigned short* __restrict__ dst,
                           float* __restrict__ rsum,
                           float* __restrict__ out) {
  int i = blockIdx.x * 256 + threadIdx.x;
  if (i >= 2885632) {                      // out zero region (2M float4)
    int o = i - 2885632;
    float4 z = {0.f, 0.f, 0.f, 0.f};
    ((float4*)out)[o] = z;
    return;
  }
  if (i >= 2883584) {                      // rsum (2048 float4)
    int z2 = i - 2883584;
    float4 z = {0.f, 0.f, 0.f, 0.f};
    ((float4*)rsum)[z2] = z;
    return;
  }
  const float* s;
  size_t si;
  if (i < 2097152) {
    s = x; si = i;
  } else {
    int j = i - 2097152;
    int z = j >> 18;
    s = (z == 0) ? w0 : ((z == 1) ? w1 : w2);
    si = j & 262143;
  }
  float4 f = ((const float4*)s)[si];
  ushort4 u;
  u.x = f2h(f.x); u.y = f2h(f.y); u.z = f2h(f.z); u.w = f2h(f.w);
  ((ushort4*)dst)[i] = u;
}

// ---------------------------------------------------------------------------
// QKV projection, grid (24, 64): x = z*8 + tn (z fast -> xh slab shared by
// all 24 blocks of a tm), y = tm.   [R11-verified, 72.5us]
//   z=0/1: C[t, f] = xh[t-slab] . W[f-tile]^T  -> kh/qh[t*1024 + f]
//   z=2  : C[d, t] = Wv[d-tile] . xh[t-slab]^T -> vT[b][d][t]  (direct)
// ---------------------------------------------------------------------------
__global__ __launch_bounds__(256) void qkv_gemm_kernel(
    const unsigned short* __restrict__ xh, const unsigned short* __restrict__ wh,
    const float* __restrict__ bk, const float* __restrict__ bq,
    const float* __restrict__ bv, unsigned short* __restrict__ kh,
    unsigned short* __restrict__ qh, unsigned short* __restrict__ vT) {
  __shared__ unsigned short As[2 * 128 * 32], Bs[2 * 128 * 32];
  const int tn = blockIdx.x & 7, z = blockIdx.x >> 3;
  const unsigned short* W = wh + (size_t)z * 1048576;
  const int tm = blockIdx.y;

  const unsigned short* Ag = (z == 2) ? (W + (size_t)tn * 128 * 1024)
                                      : (xh + (size_t)tm * 128 * 1024);
  const unsigned short* Bg = (z == 2) ? (xh + (size_t)tm * 128 * 1024)
                                      : (W + (size_t)tn * 128 * 1024);

  f32x4 acc[4][4];
  gemm128(Ag, Bg, 1024, 1024, 1024, As, Bs, acc);

  const int lane = threadIdx.x & 63, wave = threadIdx.x >> 6;
  const int wm = wave >> 1, wn = wave & 1, rr = lane & 15, qq = lane >> 4;

  if (z == 2) {
    // rows = d, cols = t; bias is per-row (float4 over reg)
#pragma unroll
    for (int i = 0; i < 4; ++i) {
      int d0 = tn * 128 + wm * 64 + i * 16 + qq * 4;
      float4 bi = *(const float4*)(bv + d0);
      float bir[4] = {bi.x, bi.y, bi.z, bi.w};
#pragma unroll
      for (int reg = 0; reg < 4; ++reg) {
        int d = d0 + reg;
#pragma unroll
        for (int j = 0; j < 4; ++j) {
          int tg = tm * 128 + wn * 64 + j * 16 + rr;  // global token
          int bb = tg >> 11, tt = tg & 2047;
          vT[((size_t)(bb * 1024 + d)) * 2048 + tt] =
              f2h(acc[i][j][reg] + bir[reg]);
        }
      }
    }
  } else {
    const float* bias = (z == 0) ? bk : bq;
    unsigned short* dst = (z == 0) ? kh : qh;
    float bj[4];
#pragma unroll
    for (int j = 0; j < 4; ++j)
      bj[j] = bias[tn * 128 + wn * 64 + j * 16 + rr];
#pragma unroll
    for (int i = 0; i < 4; ++i)
#pragma unroll
      for (int reg = 0; reg < 4; ++reg) {
        int gm = tm * 128 + wm * 64 + i * 16 + qq * 4 + reg;
#pragma unroll
        for (int j = 0; j < 4; ++j) {
          int gc = tn * 128 + wn * 64 + j * 16 + rr;
          dst[(size_t)gm * 1024 + gc] = f2h(acc[i][j][reg] + bj[j]);
        }
      }
  }
}

// ---------------------------------------------------------------------------
// scores: P[b,s,t] = exp(k[s].q[t]/32 - 4) for t<=s else 0  (f16), plus
// fused row-sum atomics. Triangular grid (136,4). BK=64 dbuf pipeline.
// [R11-verified configuration]
// ---------------------------------------------------------------------------
__global__ __launch_bounds__(256) void scores_kernel(
    const unsigned short* __restrict__ kh, const unsigned short* __restrict__ qh,
    unsigned short* __restrict__ P, float* __restrict__ rsum) {
  const int b = blockIdx.y;
  int idx = blockIdx.x;
  int ts = (int)((sqrtf(8.0f * idx + 1.0f) - 1.0f) * 0.5f);
  while ((ts + 1) * (ts + 2) / 2 <= idx) ++ts;
  while (ts * (ts + 1) / 2 > idx) --ts;
  const int tt = idx - ts * (ts + 1) / 2;
  __shared__ unsigned short As[2 * 128 * 64], Bs[2 * 128 * 64];

  f32x4 acc[4][4];
  gemm128_k64(kh + ((size_t)(b * 2048 + ts * 128)) * 1024,
              qh + ((size_t)(b * 2048 + tt * 128)) * 1024,
              1024, 1024, 1024, As, Bs, acc);

  const int lane = threadIdx.x & 63, wave = threadIdx.x >> 6;
  const int wm = wave >> 1, wn = wave & 1, rr = lane & 15, qq = lane >> 4;
  unsigned short* Pb = P + (size_t)b * 2048 * 2048;
  float* rs = rsum + b * 2048;
#pragma unroll
  for (int i = 0; i < 4; ++i)
#pragma unroll
    for (int reg = 0; reg < 4; ++reg) {
      int srow = ts * 128 + wm * 64 + i * 16 + qq * 4 + reg;
      float p = 0.f;
#pragma unroll
      for (int j = 0; j < 4; ++j) {
        int tcol = tt * 128 + wn * 64 + j * 16 + rr;
        float e = (tcol <= srow) ? __expf(acc[i][j][reg] * 0.03125f - 4.0f)
                                 : 0.0f;
        Pb[(size_t)srow * 2048 + tcol] = f2h(e);
        p += e;
      }
#pragma unroll
      for (int off = 1; off < 16; off <<= 1) p += __shfl_xor(p, off);
      if (rr == 0) atomicAdd(rs + srow, p);
    }
}

// ---------------------------------------------------------------------------
// pv (static split-K LPT): out[b,s,d] (+)= (1/rsum[b,s]) * P[b,s,:] * vT
// 512 blocks = 512 resident slots (2/CU at 64 KiB). Per (b,td) [32 groups],
// 16 bins (q) of <=2 jobs; ts>=8 tiles split at K=1024 into (8, ts-7)-unit
// chunks. Bin loads: q0..7 = 8 units, q8..15 = 9 units (makespan 9 vs 16).
//   q : job1(ts,kc)        job2(ts,kc)
//   0..7: (15,0)(15,1)(14,0)(13,0)(12,0)(11,0)(10,0)(9,0)   --
//   8 : (8,0)  + (8,1)   9 : (7)  + (0)   10: (14,1) + (9,1)
//   11: (6)    + (1)     12: (13,1)+(10,1) 13: (5)   + (2)
//   14: (12,1) + (11,1)  15: (4)  + (3)
// Split tiles (ts>=8): atomicAdd into zeroed out; unsplit: plain store.
// ---------------------------------------------------------------------------
__global__ __launch_bounds__(256) void pv_gemm_kernel(
    const unsigned short* __restrict__ P, const unsigned short* __restrict__ vT,
    const float* __restrict__ rsum, float* __restrict__ out) {
  __shared__ unsigned short As[2 * 128 * 64], Bs[2 * 128 * 64];
  static const signed char T_ts[2][16] = {
      {15, 15, 14, 13, 12, 11, 10, 9, 8, 7, 14, 6, 13, 5, 12, 4},
      {-1, -1, -1, -1, -1, -1, -1, -1, 8, 0, 9, 1, 10, 2, 11, 3}};
  static const signed char T_kc[2][16] = {
      {0, 1, 0, 0, 0, 0, 0, 0, 0, 0, 1, 0, 1, 0, 1, 0},
      {0, 0, 0, 0, 0, 0, 0, 0, 1, 0, 1, 0, 1, 0, 1, 0}};

  const int xq = blockIdx.x & 15, td = (blockIdx.x >> 4) & 7,
            b = blockIdx.x >> 7;
  const int tid = threadIdx.x;
  const int lane = tid & 63, wave = tid >> 6;
  const int wm = wave >> 1, wn = wave & 1, rr = lane & 15, qq = lane >> 4;

#pragma unroll 1
  for (int slot = 0; slot < 2; ++slot) {
    const int ts = T_ts[slot][xq];
    if (ts < 0) break;
    const bool split = (ts >= 8);
    const int kc = T_kc[slot][xq];
    const int kbeg = split ? kc * 1024 : 0;
    const int nk = split ? (kc == 0 ? 1024 : (ts + 1) * 128 - 1024)
                         : (ts + 1) * 128;

    if (slot == 1) __syncthreads();  // protect LDS from prior job's readers

    f32x4 acc[4][4];
    gemm128_k64(P + ((size_t)(b * 2048 + ts * 128)) * 2048 + kbeg,
                vT + ((size_t)(b * 1024 + td * 128)) * 2048 + kbeg,
                2048, 2048, nk, As, Bs, acc);

#pragma unroll
    for (int i = 0; i < 4; ++i) {
      int s0 = ts * 128 + wm * 64 + i * 16 + qq * 4;
      float4 r4 = *(const float4*)(rsum + b * 2048 + s0);
      float rv[4] = {__builtin_amdgcn_rcpf(r4.x), __builtin_amdgcn_rcpf(r4.y),
                     __builtin_amdgcn_rcpf(r4.z), __builtin_amdgcn_rcpf(r4.w)};
#pragma unroll
      for (int reg = 0; reg < 4; ++reg) {
        int srow = s0 + reg;
#pragma unroll
        for (int jj = 0; jj < 4; ++jj) {
          int dcol = td * 128 + wn * 64 + jj * 16 + rr;
          float v = acc[i][jj][reg] * rv[reg];
          float* dp = &out[((size_t)(b * 2048 + srow)) * 1024 + dcol];
          if (split) atomicAdd(dp, v);
          else *dp = v;
        }
      }
    }
  }
}

// ---------------------------------------------------------------------------
// launch
// ---------------------------------------------------------------------------
extern "C" void kernel_launch(void* const* d_in, const int* in_sizes, int n_in,
                              void* d_out, int out_size, void* d_ws,
                              size_t ws_size, hipStream_t stream) {
  const float* x  = (const float*)d_in[0];
  const float* Wk = (const float*)d_in[1];
  const float* bk = (const float*)d_in[2];
  const float* Wq = (const float*)d_in[3];
  const float* bq = (const float*)d_in[4];
  const float* Wv = (const float*)d_in[5];
  const float* bv = (const float*)d_in[6];
  float* out = (float*)d_out;

  char* ws = (char*)d_ws;
  const size_t MB = 1ull << 20;
  // Aliased layout (86 MB + 32 KB): P overlays xh/wh (dead by scores).
  unsigned short* xh = (unsigned short*)(ws + 0);        // 16 MB  [0,16)
  unsigned short* wh = (unsigned short*)(ws + 16 * MB);  //  6 MB  [16,22)
  unsigned short* P  = (unsigned short*)(ws + 0);        // 32 MB  [0,32) alias
  unsigned short* kh = (unsigned short*)(ws + 38 * MB);  // 16 MB  [38,54)
  unsigned short* qh = (unsigned short*)(ws + 54 * MB);  // 16 MB  [54,70)
  unsigned short* vT = (unsigned short*)(ws + 70 * MB);  // 16 MB  [70,86)
  float* rsum = (float*)(ws + 86 * MB);                  // 32 KB

  // 1) converts (x + 3 W) + zero-init of rsum and out
  cvt_kernel<<<19464, 256, 0, stream>>>(x, Wk, Wq, Wv, xh, rsum, out);
  // 2) QKV projections (R11 gemm128); z=2 operand-swapped -> writes vT
  qkv_gemm_kernel<<<dim3(24, 64), 256, 0, stream>>>(xh, wh, bk, bq, bv,
                                                    kh, qh, vT);
  // 3) masked exp(scores) + fused row-sum atomics (BK=64 dbuf)
  scores_kernel<<<dim3(136, 4), 256, 0, stream>>>(kh, qh, P, rsum);
  // 4) (P @ v) * (1/rsum) -> out (static split-K LPT, BK=64 dbuf)
  pv_gemm_kernel<<<512, 256, 0, stream>>>(P, vT, rsum, out);
}

// Round 8
// 233.176 us; speedup vs baseline: 1.2863x; 1.1184x over previous
//
#include <hip/hip_runtime.h>
#include <cstdint>

// ---------------------------------------------------------------------------
// DefaultAttention: x[4,2048,1024] fp32; k=xWk^T+bk, q=xWq^T+bq, v=xWv^T+bv;
// sim = k q^T / 32 (causal tril), attn = softmax(sim), out = attn @ v (fp32).
// R19: full revert to the R11 anchor structure (239.9us) -- cvt/qkv/scores/pv
// bodies identical, no atomics into out, no out-zeroing -- plus T1
// XCD-locality remaps on scores/pv ONLY (the isolated change):
//   scores 544 = 8 XCDs x 68 consecutive triangular jobs (kh[ts] + qh[0..ts]
//     reuse keeps each XCD's staging working set ~4-5 MB ~= its private L2;
//     previously round-robin scattered -> every XCD streamed ~32 MB).
//   pv 512 = 8 XCDs x (one b-half) x 8 ts-groups x 8 td, td slowest
//     (vT[b][td] hot across a window; P[b,ts] tile shared by its 8 td jobs
//     stays XCD-local). ts order {15,8,11,4,0,7,3,12}/{14,9,10,5,1,6,2,13}
//     balances any adjacent or +-4 block pairing on a CU to ~17 K-units
//     (kills the heavy-heavy per-CU pairing of the old y-reversed grid).
// Falsified this session: slot-count imbalance (R16 queue null, R18 LPT
// null); BK=32 for scores/pv (R6 regression); counted-vmcnt 4-buf qkv
// (R14/R15 plateau). Evidence for R19: R6 pv PMC = MfmaUtil 7.6%,
// 1.84 TB/s, FETCH 82 MB vs 50 MB working set -> L2-thrash latency stalls.
// ---------------------------------------------------------------------------

typedef __attribute__((ext_vector_type(8))) _Float16 f16x8;
typedef __attribute__((ext_vector_type(4))) float f32x4;

__device__ __forceinline__ unsigned short f2h(float x) {
  return __builtin_bit_cast(unsigned short, (_Float16)x);
}

// async global->LDS, 16B per lane; LDS dest = wave-uniform base + lane*16
__device__ __forceinline__ void lds_dma16(const void* g, void* l) {
  auto gp = reinterpret_cast<const __attribute__((address_space(1))) void*>(
      reinterpret_cast<uintptr_t>(g));
  auto lp = reinterpret_cast<__attribute__((address_space(3))) void*>(
      reinterpret_cast<uintptr_t>(l));
  __builtin_amdgcn_global_load_lds(gp, lp, 16, 0, 0);
}

// ---------------------------------------------------------------------------
// gemm128 (BK=32 dbuf, 256 thr): C[128x128] += A[128xK] * B[128xK]^T.
// XOR-swizzled LDS, double-buffered single-barrier pipeline (R4-verified).
// ---------------------------------------------------------------------------
__device__ __forceinline__ void gemm128(const unsigned short* __restrict__ Ag,
                                        const unsigned short* __restrict__ Bg,
                                        int lda, int ldb, int nk,
                                        unsigned short* As, unsigned short* Bs,
                                        f32x4 acc[4][4]) {
  const int tid = threadIdx.x;
  const int lane = tid & 63, wave = tid >> 6;
  const int wm = wave >> 1, wn = wave & 1;
  const int sr = lane >> 2;                               // staging row in chunk
  const int scb = (((lane & 3) ^ ((lane >> 3) & 3)) * 8); // swizzled src col
  const int rr = lane & 15, qq = lane >> 4;
  const int slot = ((qq ^ ((rr >> 1) & 3)) * 8);          // swizzled read col

#pragma unroll
  for (int i = 0; i < 4; ++i)
#pragma unroll
    for (int j = 0; j < 4; ++j) {
      f32x4 z = {0.f, 0.f, 0.f, 0.f};
      acc[i][j] = z;
    }

#pragma unroll
  for (int c = 0; c < 2; ++c) {
    int chunk = wave * 2 + c;
    int row = chunk * 16 + sr;
    lds_dma16(Ag + (size_t)row * lda + scb, As + chunk * 512);
    lds_dma16(Bg + (size_t)row * ldb + scb, Bs + chunk * 512);
  }

  int buf = 0;
  for (int k0 = 0; k0 < nk; k0 += 32) {
    __syncthreads();  // drains staging issued one compute-phase ago
    const int kn = k0 + 32;
    if (kn < nk) {
      unsigned short* An = As + (buf ^ 1) * 4096;
      unsigned short* Bn = Bs + (buf ^ 1) * 4096;
#pragma unroll
      for (int c = 0; c < 2; ++c) {
        int chunk = wave * 2 + c;
        int row = chunk * 16 + sr;
        lds_dma16(Ag + (size_t)row * lda + kn + scb, An + chunk * 512);
        lds_dma16(Bg + (size_t)row * ldb + kn + scb, Bn + chunk * 512);
      }
    }

    f16x8 af[4], bf[4];
    const unsigned short* Ar = As + buf * 4096 + (wm * 64 + rr) * 32 + slot;
    const unsigned short* Br = Bs + buf * 4096 + (wn * 64 + rr) * 32 + slot;
#pragma unroll
    for (int i = 0; i < 4; ++i) af[i] = *(const f16x8*)(Ar + i * 512);
#pragma unroll
    for (int j = 0; j < 4; ++j) bf[j] = *(const f16x8*)(Br + j * 512);
#pragma unroll
    for (int i = 0; i < 4; ++i)
#pragma unroll
      for (int j = 0; j < 4; ++j)
        acc[i][j] = __builtin_amdgcn_mfma_f32_16x16x32_f16(af[i], bf[j],
                                                           acc[i][j], 0, 0, 0);
    buf ^= 1;
  }
}

// ---------------------------------------------------------------------------
// gemm128_k64 (BK=64 dbuf, 256 thr): 2x16KB stages per matrix (64 KB LDS).
// R3-verified swizzle: LDS slot s of row r holds src col-block s^(r&7);
// readers use slot (cb ^ (rr&7)). 16 iters for nk=1024 -> half the barrier
// stalls; 32 MFMA/wave between barriers.
// ---------------------------------------------------------------------------
__device__ __forceinline__ void gemm128_k64(
    const unsigned short* __restrict__ Ag, const unsigned short* __restrict__ Bg,
    int lda, int ldb, int nk, unsigned short* As, unsigned short* Bs,
    f32x4 acc[4][4]) {
  const int tid = threadIdx.x;
  const int lane = tid & 63, wave = tid >> 6;
  const int wm = wave >> 1, wn = wave & 1;
  const int sr = lane >> 3;                     // staging row within 8-row chunk
  const int scb = ((lane & 7) ^ sr) * 8;        // swizzled source col (ush)
  const int rr = lane & 15, qq = lane >> 4;
  const int slot0 = ((qq) ^ (rr & 7)) * 8;      // k-half 0 read col
  const int slot1 = ((4 + qq) ^ (rr & 7)) * 8;  // k-half 1 read col

#pragma unroll
  for (int i = 0; i < 4; ++i)
#pragma unroll
    for (int j = 0; j < 4; ++j) {
      f32x4 z = {0.f, 0.f, 0.f, 0.f};
      acc[i][j] = z;
    }

  // prologue: stage k=0 into buf 0 (16 chunks of 8 rows; wave w: 4w..4w+3)
#pragma unroll
  for (int c = 0; c < 4; ++c) {
    int chunk = wave * 4 + c;
    int row = chunk * 8 + sr;
    lds_dma16(Ag + (size_t)row * lda + scb, As + chunk * 512);
    lds_dma16(Bg + (size_t)row * ldb + scb, Bs + chunk * 512);
  }

  int buf = 0;
  for (int k0 = 0; k0 < nk; k0 += 64) {
    __syncthreads();  // drains staging issued one compute-phase ago
    const int kn = k0 + 64;
    if (kn < nk) {
      unsigned short* An = As + (buf ^ 1) * 8192;
      unsigned short* Bn = Bs + (buf ^ 1) * 8192;
#pragma unroll
      for (int c = 0; c < 4; ++c) {
        int chunk = wave * 4 + c;
        int row = chunk * 8 + sr;
        lds_dma16(Ag + (size_t)row * lda + kn + scb, An + chunk * 512);
        lds_dma16(Bg + (size_t)row * ldb + kn + scb, Bn + chunk * 512);
      }
    }

    const unsigned short* Ar = As + buf * 8192 + (wm * 64 + rr) * 64;
    const unsigned short* Br = Bs + buf * 8192 + (wn * 64 + rr) * 64;
    {
      f16x8 af[4], bf[4];
#pragma unroll
      for (int i = 0; i < 4; ++i) af[i] = *(const f16x8*)(Ar + i * 1024 + slot0);
#pragma unroll
      for (int j = 0; j < 4; ++j) bf[j] = *(const f16x8*)(Br + j * 1024 + slot0);
#pragma unroll
      for (int i = 0; i < 4; ++i)
#pragma unroll
        for (int j = 0; j < 4; ++j)
          acc[i][j] = __builtin_amdgcn_mfma_f32_16x16x32_f16(af[i], bf[j],
                                                             acc[i][j], 0, 0, 0);
    }
    {
      f16x8 af[4], bf[4];
#pragma unroll
      for (int i = 0; i < 4; ++i) af[i] = *(const f16x8*)(Ar + i * 1024 + slot1);
#pragma unroll
      for (int j = 0; j < 4; ++j) bf[j] = *(const f16x8*)(Br + j * 1024 + slot1);
#pragma unroll
      for (int i = 0; i < 4; ++i)
#pragma unroll
        for (int j = 0; j < 4; ++j)
          acc[i][j] = __builtin_amdgcn_mfma_f32_16x16x32_f16(af[i], bf[j],
                                                             acc[i][j], 0, 0, 0);
    }
    buf ^= 1;
  }
}

// ---------------------------------------------------------------------------
// fp32 -> f16 convert: x then Wk,Wq,Wv into contiguous [xh | wh];
// last 8 blocks zero rsum (8192 floats).   [R11 version]
// ---------------------------------------------------------------------------
__global__ void cvt_kernel(const float* __restrict__ x,
                           const float* __restrict__ w0,
                           const float* __restrict__ w1,
                           const float* __restrict__ w2,
                           unsigned short* __restrict__ dst,
                           float* __restrict__ rsum) {
  int i = blockIdx.x * 256 + threadIdx.x;
  if (i >= 2883584) {
    int z2 = i - 2883584;
    float4 z = {0.f, 0.f, 0.f, 0.f};
    ((float4*)rsum)[z2] = z;
    return;
  }
  const float* s;
  size_t si;
  if (i < 2097152) {
    s = x; si = i;
  } else {
    int j = i - 2097152;
    int z = j >> 18;
    s = (z == 0) ? w0 : ((z == 1) ? w1 : w2);
    si = j & 262143;
  }
  float4 f = ((const float4*)s)[si];
  ushort4 u;
  u.x = f2h(f.x); u.y = f2h(f.y); u.z = f2h(f.z); u.w = f2h(f.w);
  ((ushort4*)dst)[i] = u;
}

// ---------------------------------------------------------------------------
// QKV projection, grid (24, 64): x = z*8 + tn (z fast -> xh slab shared by
// all 24 blocks of a tm), y = tm.   [R11-verified, 72.5us]
//   z=0/1: C[t, f] = xh[t-slab] . W[f-tile]^T  -> kh/qh[t*1024 + f]
//   z=2  : C[d, t] = Wv[d-tile] . xh[t-slab]^T -> vT[b][d][t]  (direct)
// ---------------------------------------------------------------------------
__global__ __launch_bounds__(256) void qkv_gemm_kernel(
    const unsigned short* __restrict__ xh, const unsigned short* __restrict__ wh,
    const float* __restrict__ bk, const float* __restrict__ bq,
    const float* __restrict__ bv, unsigned short* __restrict__ kh,
    unsigned short* __restrict__ qh, unsigned short* __restrict__ vT) {
  __shared__ unsigned short As[2 * 128 * 32], Bs[2 * 128 * 32];
  const int tn = blockIdx.x & 7, z = blockIdx.x >> 3;
  const unsigned short* W = wh + (size_t)z * 1048576;
  const int tm = blockIdx.y;

  const unsigned short* Ag = (z == 2) ? (W + (size_t)tn * 128 * 1024)
                                      : (xh + (size_t)tm * 128 * 1024);
  const unsigned short* Bg = (z == 2) ? (xh + (size_t)tm * 128 * 1024)
                                      : (W + (size_t)tn * 128 * 1024);

  f32x4 acc[4][4];
  gemm128(Ag, Bg, 1024, 1024, 1024, As, Bs, acc);

  const int lane = threadIdx.x & 63, wave = threadIdx.x >> 6;
  const int wm = wave >> 1, wn = wave & 1, rr = lane & 15, qq = lane >> 4;

  if (z == 2) {
    // rows = d, cols = t; bias is per-row (float4 over reg)
#pragma unroll
    for (int i = 0; i < 4; ++i) {
      int d0 = tn * 128 + wm * 64 + i * 16 + qq * 4;
      float4 bi = *(const float4*)(bv + d0);
      float bir[4] = {bi.x, bi.y, bi.z, bi.w};
#pragma unroll
      for (int reg = 0; reg < 4; ++reg) {
        int d = d0 + reg;
#pragma unroll
        for (int j = 0; j < 4; ++j) {
          int tg = tm * 128 + wn * 64 + j * 16 + rr;  // global token
          int bb = tg >> 11, tt = tg & 2047;
          vT[((size_t)(bb * 1024 + d)) * 2048 + tt] =
              f2h(acc[i][j][reg] + bir[reg]);
        }
      }
    }
  } else {
    const float* bias = (z == 0) ? bk : bq;
    unsigned short* dst = (z == 0) ? kh : qh;
    float bj[4];
#pragma unroll
    for (int j = 0; j < 4; ++j)
      bj[j] = bias[tn * 128 + wn * 64 + j * 16 + rr];
#pragma unroll
    for (int i = 0; i < 4; ++i)
#pragma unroll
      for (int reg = 0; reg < 4; ++reg) {
        int gm = tm * 128 + wm * 64 + i * 16 + qq * 4 + reg;
#pragma unroll
        for (int j = 0; j < 4; ++j) {
          int gc = tn * 128 + wn * 64 + j * 16 + rr;
          dst[(size_t)gm * 1024 + gc] = f2h(acc[i][j][reg] + bj[j]);
        }
      }
  }
}

// ---------------------------------------------------------------------------
// scores: P[b,s,t] = exp(k[s].q[t]/32 - 4) for t<=s else 0  (f16), plus
// fused row-sum atomics. Grid 544, XCD-chunked: J = (bid&7)*68 + (bid>>3)
// gives XCD r (= bid%8, round-robin dispatch) 68 CONSECUTIVE triangular
// jobs of one batch half -> kh[ts]/qh[0..ts] stay hot in that XCD's L2.
// BK=64 dbuf pipeline (R11 body).
// ---------------------------------------------------------------------------
__global__ __launch_bounds__(256) void scores_kernel(
    const unsigned short* __restrict__ kh, const unsigned short* __restrict__ qh,
    unsigned short* __restrict__ P, float* __restrict__ rsum) {
  const int J = (blockIdx.x & 7) * 68 + (blockIdx.x >> 3);
  const int b = J / 136;
  int idx = J - b * 136;
  int ts = (int)((sqrtf(8.0f * idx + 1.0f) - 1.0f) * 0.5f);
  while ((ts + 1) * (ts + 2) / 2 <= idx) ++ts;
  while (ts * (ts + 1) / 2 > idx) --ts;
  const int tt = idx - ts * (ts + 1) / 2;
  __shared__ unsigned short As[2 * 128 * 64], Bs[2 * 128 * 64];

  f32x4 acc[4][4];
  gemm128_k64(kh + ((size_t)(b * 2048 + ts * 128)) * 1024,
              qh + ((size_t)(b * 2048 + tt * 128)) * 1024,
              1024, 1024, 1024, As, Bs, acc);

  const int lane = threadIdx.x & 63, wave = threadIdx.x >> 6;
  const int wm = wave >> 1, wn = wave & 1, rr = lane & 15, qq = lane >> 4;
  unsigned short* Pb = P + (size_t)b * 2048 * 2048;
  float* rs = rsum + b * 2048;
#pragma unroll
  for (int i = 0; i < 4; ++i)
#pragma unroll
    for (int reg = 0; reg < 4; ++reg) {
      int srow = ts * 128 + wm * 64 + i * 16 + qq * 4 + reg;
      float p = 0.f;
#pragma unroll
      for (int j = 0; j < 4; ++j) {
        int tcol = tt * 128 + wn * 64 + j * 16 + rr;
        float e = (tcol <= srow) ? __expf(acc[i][j][reg] * 0.03125f - 4.0f)
                                 : 0.0f;
        Pb[(size_t)srow * 2048 + tcol] = f2h(e);
        p += e;
      }
#pragma unroll
      for (int off = 1; off < 16; off <<= 1) p += __shfl_xor(p, off);
      if (rr == 0) atomicAdd(rs + srow, p);
    }
}

// ---------------------------------------------------------------------------
// pv: out[b,s,d] = (1/rsum[b,s]) * sum_t P[b,s,t] * vT[b,d,t]   (fp32 out)
// Grid 512, XCD-local decode: r = bid&7 -> (b = r>>1, parity = r&1);
// i = bid>>3: td = i>>3 (slowest: vT[b][td] hot), g = i&7 -> ts from TSP
// (heavy/light orders; any adjacent or +-4 pairing on a CU ~ 17 K-units).
// P[b,ts] tile's 8 td-consumers all live on XCD r. K truncated to
// (ts+1)*128. BK=64 dbuf pipeline (R11 body), plain stores.
// ---------------------------------------------------------------------------
__global__ __launch_bounds__(256) void pv_gemm_kernel(
    const unsigned short* __restrict__ P, const unsigned short* __restrict__ vT,
    const float* __restrict__ rsum, float* __restrict__ out) {
  static const signed char TSP[2][8] = {{15, 8, 11, 4, 0, 7, 3, 12},
                                        {14, 9, 10, 5, 1, 6, 2, 13}};
  const int r = blockIdx.x & 7, i = blockIdx.x >> 3;
  const int b = r >> 1, parity = r & 1;
  const int td = i >> 3, g = i & 7;
  const int ts = TSP[parity][g];
  __shared__ unsigned short As[2 * 128 * 64], Bs[2 * 128 * 64];

  f32x4 acc[4][4];
  gemm128_k64(P + ((size_t)(b * 2048 + ts * 128)) * 2048,
              vT + ((size_t)(b * 1024 + td * 128)) * 2048,
              2048, 2048, (ts + 1) * 128, As, Bs, acc);

  const int lane = threadIdx.x & 63, wave = threadIdx.x >> 6;
  const int wm = wave >> 1, wn = wave & 1, rr = lane & 15, qq = lane >> 4;
#pragma unroll
  for (int i2 = 0; i2 < 4; ++i2) {
    int s0 = ts * 128 + wm * 64 + i2 * 16 + qq * 4;
    float4 r4 = *(const float4*)(rsum + b * 2048 + s0);
    float rv[4] = {__builtin_amdgcn_rcpf(r4.x), __builtin_amdgcn_rcpf(r4.y),
                   __builtin_amdgcn_rcpf(r4.z), __builtin_amdgcn_rcpf(r4.w)};
#pragma unroll
    for (int reg = 0; reg < 4; ++reg) {
      int srow = s0 + reg;
#pragma unroll
      for (int j = 0; j < 4; ++j) {
        int dcol = td * 128 + wn * 64 + j * 16 + rr;
        out[((size_t)(b * 2048 + srow)) * 1024 + dcol] =
            acc[i2][j][reg] * rv[reg];
      }
    }
  }
}

// ---------------------------------------------------------------------------
// launch
// ---------------------------------------------------------------------------
extern "C" void kernel_launch(void* const* d_in, const int* in_sizes, int n_in,
                              void* d_out, int out_size, void* d_ws,
                              size_t ws_size, hipStream_t stream) {
  const float* x  = (const float*)d_in[0];
  const float* Wk = (const float*)d_in[1];
  const float* bk = (const float*)d_in[2];
  const float* Wq = (const float*)d_in[3];
  const float* bq = (const float*)d_in[4];
  const float* Wv = (const float*)d_in[5];
  const float* bv = (const float*)d_in[6];
  float* out = (float*)d_out;

  char* ws = (char*)d_ws;
  const size_t MB = 1ull << 20;
  // Aliased layout (86 MB + 32 KB): P overlays xh/wh (dead by scores).
  unsigned short* xh = (unsigned short*)(ws + 0);        // 16 MB  [0,16)
  unsigned short* wh = (unsigned short*)(ws + 16 * MB);  //  6 MB  [16,22)
  unsigned short* P  = (unsigned short*)(ws + 0);        // 32 MB  [0,32) alias
  unsigned short* kh = (unsigned short*)(ws + 38 * MB);  // 16 MB  [38,54)
  unsigned short* qh = (unsigned short*)(ws + 54 * MB);  // 16 MB  [54,70)
  unsigned short* vT = (unsigned short*)(ws + 70 * MB);  // 16 MB  [70,86)
  float* rsum = (float*)(ws + 86 * MB);                  // 32 KB

  // 1) converts (x + 3 W) + rsum zero-init (last 8 blocks)
  cvt_kernel<<<11272, 256, 0, stream>>>(x, Wk, Wq, Wv, xh, rsum);
  // 2) QKV projections (R11 gemm128); z=2 operand-swapped -> writes vT
  qkv_gemm_kernel<<<dim3(24, 64), 256, 0, stream>>>(xh, wh, bk, bq, bv,
                                                    kh, qh, vT);
  // 3) masked exp(scores) + fused row-sum atomics (XCD-chunked jobs)
  scores_kernel<<<544, 256, 0, stream>>>(kh, qh, P, rsum);
  // 4) (P @ v) * (1/rsum) -> out (XCD-local groups, balanced pairing)
  pv_gemm_kernel<<<512, 256, 0, stream>>>(P, vT, rsum, out);
}